// Round 2
// baseline (26.778 us; speedup 1.0000x reference)
//
#include <hip/hip_runtime.h>

#define DD 6
#define SDIM 17
#define CAPF 20.0f
#define BIGF 1e30f
#define ROWS 256          // rows per block == blockDim.x

__global__ __launch_bounds__(256) void proj_wl1_kernel(
    const float* __restrict__ x, const float* __restrict__ s,
    float* __restrict__ out, int B)
{
    __shared__ float ls[ROWS * SDIM];   // 17408 B: s slab
    __shared__ float lx[ROWS * DD];     // 6144 B: x slab, reused for out

    const int tid = threadIdx.x;
    const size_t row0 = (size_t)blockIdx.x * ROWS;
    const bool full = (row0 + ROWS) <= (size_t)B;

    float q[DD], w[DD];

    if (full) {
        // ---- coalesced float4 staging: global -> LDS ----
        const float4* gs = reinterpret_cast<const float4*>(s + row0 * SDIM);
        float4* lsv = reinterpret_cast<float4*>(ls);
        for (int t = tid; t < ROWS * SDIM / 4; t += ROWS) lsv[t] = gs[t];

        const float4* gx = reinterpret_cast<const float4*>(x + row0 * DD);
        float4* lxv = reinterpret_cast<float4*>(lx);
        for (int t = tid; t < ROWS * DD / 4; t += ROWS) lxv[t] = gx[t];

        __syncthreads();

#pragma unroll
        for (int i = 0; i < DD; ++i) q[i] = lx[tid * DD + i];
#pragma unroll
        for (int i = 0; i < DD; ++i) w[i] = fabsf(ls[tid * SDIM + 11 + i]);
    } else {
        // ---- tail block: direct bounds-checked loads ----
        size_t row = row0 + tid;
        bool ok = row < (size_t)B;
        const float* xp = x + row * DD;
        const float* sp = s + row * SDIM + 11;
#pragma unroll
        for (int i = 0; i < DD; ++i) q[i] = ok ? xp[i] : 0.f;
#pragma unroll
        for (int i = 0; i < DD; ++i) w[i] = ok ? fabsf(sp[i]) : 0.f;
    }

    // ---- per-row closed-form projection (exact reference semantics) ----
    float a[DD], r[DD], wq[DD], w2[DD];
    float total = 0.f;
#pragma unroll
    for (int i = 0; i < DD; ++i) {
        a[i]  = fabsf(q[i]);
        wq[i] = w[i] * a[i];
        w2[i] = w[i] * w[i];
        total += wq[i];
        r[i]  = (w[i] > 0.f) ? (a[i] / w[i]) : BIGF;
    }

    // sort (r, wq, w2) descending by r — 15-cswap unrolled bubble network
#pragma unroll
    for (int i = 0; i < DD - 1; ++i) {
#pragma unroll
        for (int j = 0; j < DD - 1 - i; ++j) {
            bool sw = r[j] < r[j + 1];
            float t0 = r[j], t1 = wq[j], t2 = w2[j];
            r[j]  = sw ? r[j + 1]  : r[j];
            wq[j] = sw ? wq[j + 1] : wq[j];
            w2[j] = sw ? w2[j + 1] : w2[j];
            r[j + 1]  = sw ? t0 : r[j + 1];
            wq[j + 1] = sw ? t1 : wq[j + 1];
            w2[j + 1] = sw ? t2 : w2[j + 1];
        }
    }

    float cwq = 0.f, cw2 = 0.f;
    float lamk[DD];
    int m = 0;
#pragma unroll
    for (int k = 0; k < DD; ++k) {
        cwq += wq[k];
        cw2 += w2[k];
        float safe = (cw2 > 0.f) ? cw2 : 1.f;
        lamk[k] = (cwq - CAPF) / safe;
        bool valid = (r[k] > lamk[k]) && (cw2 > 0.f);
        m += valid ? 1 : 0;
    }
    int ks = m - 1;
    if (ks < 0) ks = 0;
    float lam = lamk[0];
#pragma unroll
    for (int k = 1; k < DD; ++k) lam = (ks == k) ? lamk[k] : lam;
    lam = (total > CAPF) ? fmaxf(lam, 0.f) : 0.f;

    float o[DD];
#pragma unroll
    for (int i = 0; i < DD; ++i) {
        float mag = fmaxf(a[i] - lam * w[i], 0.f);
        float sgn = (q[i] > 0.f) ? 1.f : ((q[i] < 0.f) ? -1.f : 0.f);
        o[i] = sgn * mag;
    }

    if (full) {
        // ---- write o via LDS, then coalesced float4 store ----
        __syncthreads();   // everyone done reading lx as input
#pragma unroll
        for (int i = 0; i < DD; ++i) lx[tid * DD + i] = o[i];
        __syncthreads();

        float4* gout = reinterpret_cast<float4*>(out + row0 * DD);
        const float4* lxv = reinterpret_cast<const float4*>(lx);
        for (int t = tid; t < ROWS * DD / 4; t += ROWS) gout[t] = lxv[t];
    } else {
        size_t row = row0 + tid;
        if (row < (size_t)B) {
            float* op = out + row * DD;
#pragma unroll
            for (int i = 0; i < DD; ++i) op[i] = o[i];
        }
    }
}

extern "C" void kernel_launch(void* const* d_in, const int* in_sizes, int n_in,
                              void* d_out, int out_size, void* d_ws, size_t ws_size,
                              hipStream_t stream)
{
    const float* x = (const float*)d_in[0];
    const float* s = (const float*)d_in[1];
    float* out = (float*)d_out;
    int B = in_sizes[0] / DD;

    const int block = ROWS;
    int grid = (B + block - 1) / block;
    proj_wl1_kernel<<<grid, block, 0, stream>>>(x, s, out, B);
}